// Round 1
// baseline (524.735 us; speedup 1.0000x reference)
//
#include <hip/hip_runtime.h>

// Reference reduces to a center crop (coords are fp32-exact integers i+16.0):
//   data_out[b,c,i,j,k] = data[b,c,i+16,j+16,k+16]
//   seg_out  = seg[:, :, 16:176, 16:176, 16:176]
// Shapes: in 2x (4,2,192,192,192) f32, out 2x (4,2,160,160,160) f32 concat-flat.
//
// Structure: one block per (bc, d) slab -> 8*160 = 1280 blocks, exactly 5/CU,
// whole grid co-resident (no workgroup churn). Block = 320 threads = 8 rows
// of 40 float4. Each thread copies 20 f4 per tensor (rows h0, h0+8, ..,
// h0+152) with pure additive addressing: ONE div/mod per thread, then
// constant increments (src += 48*k f4, o += 40*k f4).
// Inner group issues 8 independent loads (8 KB/wave in flight) before the
// 8 stores -> latency fully covered. Plain loads (m13 copy recipe), nt
// stores (output never re-read; keep write stream out of L2).

constexpr unsigned P      = 160;              // patch edge
constexpr unsigned S      = 192;              // source edge
constexpr unsigned OFF    = 16;               // crop offset
constexpr unsigned BC     = 8;                // 4*2 volumes per tensor
constexpr unsigned ROW4   = P / 4;            // 40 f4 per out row
constexpr unsigned SROW4  = S / 4;            // 48 f4 per src row
constexpr unsigned SPLANE4= S * S / 4;        // 9216 f4 per src plane
constexpr unsigned SVOL4  = S * S * S / 4;    // 1769472 f4 per src volume
constexpr unsigned OUT4   = BC * P * P * ROW4; // 8,192,000 f4 per tensor

using f4 = __attribute__((ext_vector_type(4))) float;

__global__ __launch_bounds__(320) void crop_copy_kernel(
    const f4* __restrict__ data,
    const f4* __restrict__ seg,
    f4* __restrict__ out)
{
    const unsigned t  = threadIdx.x;
    const unsigned h0 = t / ROW4;             // 0..7  (row within 8-row stripe)
    const unsigned w4 = t - h0 * ROW4;        // 0..39 (f4 within row)
    const unsigned bc = blockIdx.x / P;       // 0..7
    const unsigned d  = blockIdx.x - bc * P;  // 0..159

    unsigned src = bc * SVOL4 + (d + OFF) * SPLANE4 + (h0 + OFF) * SROW4
                 + (OFF / 4) + w4;
    unsigned o   = blockIdx.x * (P * ROW4) + h0 * ROW4 + w4;

    // 20 rows/thread in 5 groups of 4; within a group rows are 8 apart.
    for (unsigned g = 0; g < 5; ++g) {
        f4 a0 = data[src];
        f4 a1 = data[src +  8 * SROW4];
        f4 a2 = data[src + 16 * SROW4];
        f4 a3 = data[src + 24 * SROW4];
        f4 b0 = seg[src];
        f4 b1 = seg[src +  8 * SROW4];
        f4 b2 = seg[src + 16 * SROW4];
        f4 b3 = seg[src + 24 * SROW4];

        __builtin_nontemporal_store(a0, &out[o]);
        __builtin_nontemporal_store(a1, &out[o +  8 * ROW4]);
        __builtin_nontemporal_store(a2, &out[o + 16 * ROW4]);
        __builtin_nontemporal_store(a3, &out[o + 24 * ROW4]);
        __builtin_nontemporal_store(b0, &out[o + OUT4]);
        __builtin_nontemporal_store(b1, &out[o + OUT4 +  8 * ROW4]);
        __builtin_nontemporal_store(b2, &out[o + OUT4 + 16 * ROW4]);
        __builtin_nontemporal_store(b3, &out[o + OUT4 + 24 * ROW4]);

        src += 32 * SROW4;   // advance 32 rows
        o   += 32 * ROW4;
    }
}

extern "C" void kernel_launch(void* const* d_in, const int* in_sizes, int n_in,
                              void* d_out, int out_size, void* d_ws, size_t ws_size,
                              hipStream_t stream)
{
    const f4* data = (const f4*)d_in[0];
    const f4* seg  = (const f4*)d_in[1];
    f4* out = (f4*)d_out;

    constexpr unsigned block = 320;           // 5 waves, 8 rows x 40 f4
    constexpr unsigned grid  = BC * P;        // 1280 blocks = 5 per CU, no tail
    crop_copy_kernel<<<grid, block, 0, stream>>>(data, seg, out);
}

// Round 2
// 484.766 us; speedup vs baseline: 1.0825x; 1.0825x over previous
//
#include <hip/hip_runtime.h>

// Reference reduces to a center crop (coords are fp32-exact integers i+16.0):
//   data_out[b,c,i,j,k] = data[b,c,i+16,j+16,k+16]
//   seg_out  = seg[:, :, 16:176, 16:176, 16:176]
// Shapes: in 2x (4,2,192,192,192) f32, out 2x (4,2,160,160,160) f32 concat-flat.
//
// R0 (1 f4/tensor/thread, 32000 blocks, nt): 161 us. R1 (coarse 1280-block
// slabs, 20 f4/thread): 172 us -- REGRESSED, OccupancyPercent 42% => scheduler
// imbalance with only 5 blocks/CU, no slack. This round: keep R0's
// fine-grained self-balancing linear sweep + nt flags, but give each thread
// 4 f4 per tensor (8 independent loads in flight, ~8 KB/wave MLP) to cut
// wave churn 4x and cover HBM latency within a wave. Grid = 8000 blocks
// (~31/CU) -- still self-balancing.
//
// Each block owns 1024 consecutive out-f4 per tensor; thread t handles
// o = base + t + 256k, k=0..3. All loads issued before any store.
// VALU is ~1% busy, so the 4x div/mod address chains are free.

constexpr unsigned P    = 160;                 // patch edge
constexpr unsigned S    = 192;                 // source edge
constexpr unsigned OFF  = 16;                  // crop offset
constexpr unsigned BC   = 8;                   // 4*2 volumes per tensor
constexpr unsigned ROW4 = P / 4;               // 40 f4 per out row
constexpr unsigned SROW4   = S / 4;            // 48
constexpr unsigned SPLANE4 = S * S / 4;        // 9216
constexpr unsigned SVOL4   = S * S * S / 4;    // 1769472
constexpr unsigned OUT4 = BC * P * P * ROW4;   // 8,192,000 f4 per tensor

using f4 = __attribute__((ext_vector_type(4))) float;

__global__ __launch_bounds__(256) void crop_copy_kernel(
    const f4* __restrict__ data,
    const f4* __restrict__ seg,
    f4* __restrict__ out)
{
    const unsigned o0 = blockIdx.x * 1024u + threadIdx.x;  // + 256k, k=0..3

    unsigned src[4];
#pragma unroll
    for (unsigned k = 0; k < 4; ++k) {
        const unsigned o   = o0 + 256u * k;
        const unsigned w4  = o % ROW4;
        const unsigned row = o / ROW4;
        const unsigned h   = row % P;
        const unsigned t   = row / P;
        const unsigned d   = t % P;
        const unsigned bc  = t / P;
        src[k] = bc * SVOL4 + (d + OFF) * SPLANE4 + (h + OFF) * SROW4
               + (OFF / 4) + w4;
    }

    // 8 independent loads in flight before any store.
    f4 a0 = __builtin_nontemporal_load(&data[src[0]]);
    f4 a1 = __builtin_nontemporal_load(&data[src[1]]);
    f4 a2 = __builtin_nontemporal_load(&data[src[2]]);
    f4 a3 = __builtin_nontemporal_load(&data[src[3]]);
    f4 b0 = __builtin_nontemporal_load(&seg[src[0]]);
    f4 b1 = __builtin_nontemporal_load(&seg[src[1]]);
    f4 b2 = __builtin_nontemporal_load(&seg[src[2]]);
    f4 b3 = __builtin_nontemporal_load(&seg[src[3]]);

    __builtin_nontemporal_store(a0, &out[o0]);
    __builtin_nontemporal_store(a1, &out[o0 + 256u]);
    __builtin_nontemporal_store(a2, &out[o0 + 512u]);
    __builtin_nontemporal_store(a3, &out[o0 + 768u]);
    __builtin_nontemporal_store(b0, &out[o0 + OUT4]);
    __builtin_nontemporal_store(b1, &out[o0 + OUT4 + 256u]);
    __builtin_nontemporal_store(b2, &out[o0 + OUT4 + 512u]);
    __builtin_nontemporal_store(b3, &out[o0 + OUT4 + 768u]);
}

extern "C" void kernel_launch(void* const* d_in, const int* in_sizes, int n_in,
                              void* d_out, int out_size, void* d_ws, size_t ws_size,
                              hipStream_t stream)
{
    const f4* data = (const f4*)d_in[0];
    const f4* seg  = (const f4*)d_in[1];
    f4* out = (f4*)d_out;

    constexpr unsigned block = 256;
    constexpr unsigned grid  = OUT4 / 1024;    // 8000 blocks, no tail
    crop_copy_kernel<<<grid, block, 0, stream>>>(data, seg, out);
}